// Round 8
// baseline (813.206 us; speedup 1.0000x reference)
//
#include <hip/hip_runtime.h>
#include <hip/hip_bf16.h>
#include <math.h>

// Problem constants (from reference setup): b=4, c=128, h=16, w=16
//   D    = 128*16*16 = 32768 floats per (n,b) slice
//   DIM4 = D/4 = 8192 float4 per slice; 128 KB per slice
#define BQ    4
#define DIM   32768
#define DIM4  8192
#define ITEM4 32768   // (4*32768)/4 float4 per memory item
#define EPS   1e-8f
#define QREG  16      // float4 per thread of register-resident query slice
#define NSTREAM 2048  // streaming blocks (+1 qnorm block)

using f4 = __attribute__((ext_vector_type(4))) float;

// ---------------- Fused Kernel: qnorm || dot-stream -> last block top-k ----------------
// Block 0: query norms (runs concurrently with the stream).
// Blocks 1..NSTREAM: R7-proven streaming — block pinned to batch row b, query
// slice in registers, whole 128 KB item in flight, nontemporal loads (zero
// reuse), one __syncthreads per item via double-buffered LDS reduce.
// Every block then: __threadfence(); __syncthreads(); thread0 takes a ticket.
// The block drawing the LAST ticket runs top-k + softmax inline (rocPRIM-style
// last-block pattern; deterministic regardless of dispatch order).
__global__ __launch_bounds__(512) void dot_topk_kernel(
        const float* __restrict__ q, const float* __restrict__ mem,
        float2* __restrict__ dn, float* __restrict__ qn2,
        int* __restrict__ counter,
        const int* __restrict__ kp,
        float* __restrict__ weights, int* __restrict__ topidx,
        int N) {
    const int wid  = threadIdx.x >> 6;
    const int lane = threadIdx.x & 63;

    __shared__ float sd[2][8], sn[2][8];
    __shared__ float sq[8];
    __shared__ int   sticket;

    if (blockIdx.x == 0) {
        // --- query norms: wave w handles (b = w&3, half = w>>2) ---
        const int b = wid & 3, half = wid >> 2;
        const f4* q4 = (const f4*)(q + (size_t)b * DIM) + half * (DIM4 / 2);
        float s = 0.f;
        #pragma unroll 8
        for (int j = 0; j < 64; ++j) {          // 64 lanes x 64 = half slice
            f4 v = q4[lane + j * 64];
            s += v.x * v.x + v.y * v.y + v.z * v.z + v.w * v.w;
        }
        #pragma unroll
        for (int off = 32; off > 0; off >>= 1) s += __shfl_down(s, off);
        if (lane == 0) sq[wid] = s;
        __syncthreads();
        if (threadIdx.x < BQ) qn2[threadIdx.x] = sq[threadIdx.x] + sq[threadIdx.x + 4];
    } else {
        // --- streaming: one (n,b) item per iteration, full-window loads ---
        const int sb   = blockIdx.x - 1;
        const int b    = sb & 3;
        const int bn   = sb >> 2;
        const int nblk = NSTREAM >> 2;

        const f4* q4 = (const f4*)(q + (size_t)b * DIM);
        f4 qr[QREG];
        #pragma unroll
        for (int j = 0; j < QREG; ++j) qr[j] = q4[threadIdx.x + j * 512];

        int buf = 0;
        for (int n = bn; n < N; n += nblk, buf ^= 1) {
            const f4* m4 = (const f4*)(mem + ((size_t)n * BQ + b) * DIM);
            float dot = 0.f, nrm = 0.f;
            #pragma unroll
            for (int j = 0; j < QREG; ++j) {
                f4 m = __builtin_nontemporal_load(m4 + threadIdx.x + j * 512);
                f4 a = qr[j];
                dot += a.x * m.x + a.y * m.y + a.z * m.z + a.w * m.w;
                nrm += m.x * m.x + m.y * m.y + m.z * m.z + m.w * m.w;
            }
            #pragma unroll
            for (int off = 32; off > 0; off >>= 1) {
                dot += __shfl_down(dot, off);
                nrm += __shfl_down(nrm, off);
            }
            if (lane == 0) { sd[buf][wid] = dot; sn[buf][wid] = nrm; }
            __syncthreads();
            if (threadIdx.x == 0) {
                float d = 0.f, n2 = 0.f;
                #pragma unroll
                for (int w = 0; w < 8; ++w) { d += sd[buf][w]; n2 += sn[buf][w]; }
                dn[n * BQ + b] = make_float2(d, n2);
            }
            // no trailing barrier: buf^1 next; buf rewritten only after the
            // next intervening barrier.
        }
    }

    // --- release my writes, take a ticket ---
    __threadfence();
    __syncthreads();
    if (threadIdx.x == 0) sticket = atomicAdd(counter, 1);
    __syncthreads();
    if (sticket != NSTREAM) return;   // tickets 0..NSTREAM; last of NSTREAM+1 blocks

    // ================= last block: top-k + softmax =================
    __threadfence();   // acquire side
    const int k = *kp;

    __shared__ float qden[BQ];
    __shared__ float swv[2][8];
    __shared__ int   swi[2][8];
    __shared__ float tvals[64];
    __shared__ int   tidxs[64];

    if (threadIdx.x < BQ) qden[threadIdx.x] = fmaxf(sqrtf(qn2[threadIdx.x]), EPS);
    __syncthreads();

    // sims in registers: thread t owns n = t, t+512, t+1024, t+1536
    float sv[4];
    #pragma unroll
    for (int i = 0; i < 4; ++i) {
        const int n = threadIdx.x + i * 512;
        if (n < N) {
            const f4* p4 = (const f4*)(dn + (size_t)n * BQ);
            f4 v0 = p4[0];  // (dot0, nrm0, dot1, nrm1)
            f4 v1 = p4[1];  // (dot2, nrm2, dot3, nrm3)
            float s = v0.x / (qden[0] * fmaxf(sqrtf(v0.y), EPS))
                    + v0.z / (qden[1] * fmaxf(sqrtf(v0.w), EPS))
                    + v1.x / (qden[2] * fmaxf(sqrtf(v1.y), EPS))
                    + v1.z / (qden[3] * fmaxf(sqrtf(v1.w), EPS));
            sv[i] = s * (1.0f / BQ);
        } else {
            sv[i] = -INFINITY;
        }
    }

    // iterative top-k (lowest-index tie-break, matches jax.lax.top_k);
    // one barrier per round via parity-buffered wave winners.
    for (int it = 0; it < k; ++it) {
        const int par = it & 1;
        float best = sv[0];
        int bi = threadIdx.x;
        #pragma unroll
        for (int i = 1; i < 4; ++i) {
            if (sv[i] > best) { best = sv[i]; bi = threadIdx.x + i * 512; }
        }
        #pragma unroll
        for (int off = 32; off > 0; off >>= 1) {
            float ov = __shfl_down(best, off);
            int   oi = __shfl_down(bi, off);
            if (ov > best || (ov == best && oi < bi)) { best = ov; bi = oi; }
        }
        if (lane == 0) { swv[par][wid] = best; swi[par][wid] = bi; }
        __syncthreads();
        float bv = swv[par][0]; int bx = swi[par][0];
        #pragma unroll
        for (int w = 1; w < 8; ++w) {
            if (swv[par][w] > bv || (swv[par][w] == bv && swi[par][w] < bx)) {
                bv = swv[par][w]; bx = swi[par][w];
            }
        }
        if (threadIdx.x == 0) { tvals[it] = bv; tidxs[it] = bx; }
        if ((bx & 511) == (int)threadIdx.x) sv[bx >> 9] = -INFINITY;
    }

    if (threadIdx.x == 0) {
        float m = tvals[0];          // descending: first is the max
        float sum = 0.f;
        for (int i = 0; i < k; ++i) sum += expf(tvals[i] - m);
        float inv = 1.0f / sum;
        for (int i = 0; i < k; ++i) {
            weights[i] = expf(tvals[i] - m) * inv;
            topidx[i]  = tidxs[i];
        }
    }
}

// ---------------- Kernel D: weighted gather-sum of selected items ----------------
__global__ __launch_bounds__(128) void wsum_kernel(
        const float* __restrict__ mem,
        const float* __restrict__ weights,
        const int* __restrict__ topidx,
        const int* __restrict__ kp,
        float* __restrict__ out) {
    const int k = *kp;
    __shared__ float w[64];
    __shared__ int   id[64];
    if ((int)threadIdx.x < k) {
        w[threadIdx.x]  = weights[threadIdx.x];
        id[threadIdx.x] = topidx[threadIdx.x];
    }
    __syncthreads();
    const int t = blockIdx.x * blockDim.x + threadIdx.x;   // float4 index within item
    if (t >= ITEM4) return;
    const f4* m4 = (const f4*)mem;
    f4 acc = {0.f, 0.f, 0.f, 0.f};
    #pragma unroll 4
    for (int j = 0; j < k; ++j) {
        f4 v = __builtin_nontemporal_load(m4 + (size_t)id[j] * ITEM4 + t);
        float wj = w[j];
        acc.x += wj * v.x; acc.y += wj * v.y; acc.z += wj * v.z; acc.w += wj * v.w;
    }
    ((f4*)out)[t] = acc;
}

extern "C" void kernel_launch(void* const* d_in, const int* in_sizes, int n_in,
                              void* d_out, int out_size, void* d_ws, size_t ws_size,
                              hipStream_t stream) {
    const float* q   = (const float*)d_in[0];   // [4,128,16,16]
    const float* mem = (const float*)d_in[1];   // [N,4,128,16,16]
    const int*   kp  = (const int*)d_in[2];     // scalar k
    float* out = (float*)d_out;

    const int N = in_sizes[1] / (BQ * DIM);     // 2000

    // Workspace layout:
    float2* dn      = (float2*)d_ws;                    // N*BQ float2 = 64 KB
    float*  wts     = (float*)(dn + (size_t)N * BQ);    // 64 f
    int*    tidx    = (int*)(wts + 64);                 // 64 i
    float*  qn2     = (float*)(tidx + 64);              // 4 f (pad to 8)
    int*    counter = (int*)(qn2 + 8);                  // 1 i

    // Ticket counter must start at 0 every launch (graph-safe async memset).
    hipMemsetAsync(counter, 0, sizeof(int), stream);

    dot_topk_kernel<<<NSTREAM + 1, 512, 0, stream>>>(q, mem, dn, qn2, counter,
                                                     kp, wts, tidx, N);
    wsum_kernel<<<(ITEM4 + 127) / 128, 128, 0, stream>>>(mem, wts, tidx, kp, out);
}

// Round 9
// 191.224 us; speedup vs baseline: 4.2526x; 4.2526x over previous
//
#include <hip/hip_runtime.h>
#include <hip/hip_bf16.h>
#include <math.h>

// Problem constants (from reference setup): b=4, c=128, h=16, w=16
//   D    = 128*16*16 = 32768 floats per (n,b) slice
//   DIM4 = D/4 = 8192 float4 per slice; 128 KB per slice
#define BQ    4
#define DIM   32768
#define DIM4  8192
#define ITEM4 32768   // (4*32768)/4 float4 per memory item
#define EPS   1e-8f
#define QREG  16      // float4 per thread of register-resident query slice
#define NSTREAM 2048  // streaming blocks; blocks NSTREAM..NSTREAM+3 do qnorm

using f4 = __attribute__((ext_vector_type(4))) float;

// ---------------- Kernel B: dot-stream + ride-along qnorm blocks ----------------
// Blocks 0..NSTREAM-1: R7-proven streaming — block pinned to batch row b
// (query slice in registers), whole 128 KB item in flight per iteration,
// nontemporal loads (zero reuse), one __syncthreads per item via
// double-buffered LDS reduce.
// Blocks NSTREAM..NSTREAM+3: tiny early-return branch computing qn2[b],
// overlapped with the stream. Branch uses ~10 VGPR, so it cannot raise the
// streaming path's register allocation (R8 lesson: fusing the large-state
// top-k tail spilled qr[] to scratch and cost 4x).
__global__ __launch_bounds__(512) void dot_norm_kernel(
        const float* __restrict__ q, const float* __restrict__ mem,
        float2* __restrict__ dn, float* __restrict__ qn2, int N) {
    const int wid  = threadIdx.x >> 6;
    const int lane = threadIdx.x & 63;

    if (blockIdx.x >= NSTREAM) {
        // ---- qnorm for b = blockIdx.x - NSTREAM: 512 thr x 16 f4 = slice ----
        const int b = blockIdx.x - NSTREAM;
        const f4* q4 = (const f4*)(q + (size_t)b * DIM);
        float s = 0.f;
        #pragma unroll 4
        for (int j = 0; j < QREG; ++j) {
            f4 v = q4[threadIdx.x + j * 512];
            s += v.x * v.x + v.y * v.y + v.z * v.z + v.w * v.w;
        }
        #pragma unroll
        for (int off = 32; off > 0; off >>= 1) s += __shfl_down(s, off);
        __shared__ float sq[8];
        if (lane == 0) sq[wid] = s;
        __syncthreads();
        if (threadIdx.x == 0) {
            float tot = 0.f;
            #pragma unroll
            for (int w = 0; w < 8; ++w) tot += sq[w];
            qn2[b] = tot;
        }
        return;
    }

    const int b    = blockIdx.x & 3;
    const int bn   = blockIdx.x >> 2;       // block index within this b
    const int nblk = NSTREAM >> 2;          // blocks per b
    const f4* q4 = (const f4*)(q + (size_t)b * DIM);
    f4 qr[QREG];
    #pragma unroll
    for (int j = 0; j < QREG; ++j) qr[j] = q4[threadIdx.x + j * 512];

    __shared__ float sd[2][8], sn[2][8];
    int buf = 0;

    for (int n = bn; n < N; n += nblk, buf ^= 1) {
        const f4* m4 = (const f4*)(mem + ((size_t)n * BQ + b) * DIM);
        float dot = 0.f, nrm = 0.f;
        #pragma unroll
        for (int j = 0; j < QREG; ++j) {
            f4 m = __builtin_nontemporal_load(m4 + threadIdx.x + j * 512);
            f4 a = qr[j];
            dot += a.x * m.x + a.y * m.y + a.z * m.z + a.w * m.w;
            nrm += m.x * m.x + m.y * m.y + m.z * m.z + m.w * m.w;
        }
        #pragma unroll
        for (int off = 32; off > 0; off >>= 1) {
            dot += __shfl_down(dot, off);
            nrm += __shfl_down(nrm, off);
        }
        if (lane == 0) { sd[buf][wid] = dot; sn[buf][wid] = nrm; }
        __syncthreads();
        if (threadIdx.x == 0) {
            float d = 0.f, n2 = 0.f;
            #pragma unroll
            for (int w = 0; w < 8; ++w) { d += sd[buf][w]; n2 += sn[buf][w]; }
            dn[n * BQ + b] = make_float2(d, n2);
        }
        // No trailing barrier: next iteration writes buf^1; buf is only
        // rewritten two iterations on, after an intervening barrier.
    }
}

// ---------------- Kernel C: sims -> top-k -> softmax ----------------
// Single block, 512 threads; qn2 precomputed (overlapped with the stream).
// sims in registers (4/thread); each of the k rounds costs ONE barrier via
// parity-buffered wave winners + redundant block reduce in all threads.
__global__ __launch_bounds__(512) void topk_softmax_kernel(
        const float* __restrict__ qn2,
        const float2* __restrict__ dn,
        const int* __restrict__ kp,
        float* __restrict__ weights,
        int* __restrict__ topidx,
        int N) {
    const int k    = *kp;
    const int lane = threadIdx.x & 63;
    const int wid  = threadIdx.x >> 6;

    __shared__ float qden[BQ];
    __shared__ float swv[2][8];
    __shared__ int   swi[2][8];
    __shared__ float tvals[64];
    __shared__ int   tidxs[64];

    if (threadIdx.x < BQ) qden[threadIdx.x] = fmaxf(sqrtf(qn2[threadIdx.x]), EPS);
    __syncthreads();

    // sims in registers: thread t owns n = t, t+512, t+1024, t+1536
    float sv[4];
    #pragma unroll
    for (int i = 0; i < 4; ++i) {
        const int n = threadIdx.x + i * 512;
        if (n < N) {
            const f4* p4 = (const f4*)(dn + (size_t)n * BQ);
            f4 v0 = p4[0];  // (dot0, nrm0, dot1, nrm1)
            f4 v1 = p4[1];  // (dot2, nrm2, dot3, nrm3)
            float s = v0.x / (qden[0] * fmaxf(sqrtf(v0.y), EPS))
                    + v0.z / (qden[1] * fmaxf(sqrtf(v0.w), EPS))
                    + v1.x / (qden[2] * fmaxf(sqrtf(v1.y), EPS))
                    + v1.z / (qden[3] * fmaxf(sqrtf(v1.w), EPS));
            sv[i] = s * (1.0f / BQ);
        } else {
            sv[i] = -INFINITY;
        }
    }

    // iterative top-k (lowest-index tie-break, matches jax.lax.top_k)
    for (int it = 0; it < k; ++it) {
        const int par = it & 1;
        float best = sv[0];
        int bi = threadIdx.x;
        #pragma unroll
        for (int i = 1; i < 4; ++i) {
            if (sv[i] > best) { best = sv[i]; bi = threadIdx.x + i * 512; }
        }
        #pragma unroll
        for (int off = 32; off > 0; off >>= 1) {
            float ov = __shfl_down(best, off);
            int   oi = __shfl_down(bi, off);
            if (ov > best || (ov == best && oi < bi)) { best = ov; bi = oi; }
        }
        if (lane == 0) { swv[par][wid] = best; swi[par][wid] = bi; }
        __syncthreads();
        float bv = swv[par][0]; int bx = swi[par][0];
        #pragma unroll
        for (int w = 1; w < 8; ++w) {
            if (swv[par][w] > bv || (swv[par][w] == bv && swi[par][w] < bx)) {
                bv = swv[par][w]; bx = swi[par][w];
            }
        }
        if (threadIdx.x == 0) { tvals[it] = bv; tidxs[it] = bx; }
        if ((bx & 511) == (int)threadIdx.x) sv[bx >> 9] = -INFINITY;
    }

    if (threadIdx.x == 0) {
        float m = tvals[0];          // descending: first is the max
        float sum = 0.f;
        for (int i = 0; i < k; ++i) sum += expf(tvals[i] - m);
        float inv = 1.0f / sum;
        for (int i = 0; i < k; ++i) {
            weights[i] = expf(tvals[i] - m) * inv;
            topidx[i]  = tidxs[i];
        }
    }
}

// ---------------- Kernel D: weighted gather-sum of selected items ----------------
__global__ __launch_bounds__(128) void wsum_kernel(
        const float* __restrict__ mem,
        const float* __restrict__ weights,
        const int* __restrict__ topidx,
        const int* __restrict__ kp,
        float* __restrict__ out) {
    const int k = *kp;
    __shared__ float w[64];
    __shared__ int   id[64];
    if ((int)threadIdx.x < k) {
        w[threadIdx.x]  = weights[threadIdx.x];
        id[threadIdx.x] = topidx[threadIdx.x];
    }
    __syncthreads();
    const int t = blockIdx.x * blockDim.x + threadIdx.x;   // float4 index within item
    if (t >= ITEM4) return;
    const f4* m4 = (const f4*)mem;
    f4 acc = {0.f, 0.f, 0.f, 0.f};
    #pragma unroll 4
    for (int j = 0; j < k; ++j) {
        f4 v = __builtin_nontemporal_load(m4 + (size_t)id[j] * ITEM4 + t);
        float wj = w[j];
        acc.x += wj * v.x; acc.y += wj * v.y; acc.z += wj * v.z; acc.w += wj * v.w;
    }
    ((f4*)out)[t] = acc;
}

extern "C" void kernel_launch(void* const* d_in, const int* in_sizes, int n_in,
                              void* d_out, int out_size, void* d_ws, size_t ws_size,
                              hipStream_t stream) {
    const float* q   = (const float*)d_in[0];   // [4,128,16,16]
    const float* mem = (const float*)d_in[1];   // [N,4,128,16,16]
    const int*   kp  = (const int*)d_in[2];     // scalar k
    float* out = (float*)d_out;

    const int N = in_sizes[1] / (BQ * DIM);     // 2000

    // Workspace layout:
    float2* dn   = (float2*)d_ws;                    // N*BQ float2 = 64 KB
    float*  wts  = (float*)(dn + (size_t)N * BQ);    // 64 f
    int*    tidx = (int*)(wts + 64);                 // 64 i
    float*  qn2  = (float*)(tidx + 64);              // 4 f

    dot_norm_kernel<<<NSTREAM + BQ, 512, 0, stream>>>(q, mem, dn, qn2, N);
    topk_softmax_kernel<<<1, 512, 0, stream>>>(qn2, dn, kp, wts, tidx, N);
    wsum_kernel<<<(ITEM4 + 127) / 128, 128, 0, stream>>>(mem, wts, tidx, kp, out);
}